// Round 21
// baseline (79.930 us; speedup 1.0000x reference)
//
#include <hip/hip_runtime.h>
#include <stdint.h>

#define OUT_HW    14
#define NBINS     196               // 14*14
#define C_TOTAL   256
#define C_PER_BLK 32
#define NOCT      (C_PER_BLK / 8)   // 4 channel-octets per block (2 quads each)
#define NBOXES    512
#define BUFL      1280              // 16B cells per buffer (worst ~1232: NR=56, TWL<=22)
#define MAXG      2                 // float4 groups per thread: worst NG ~336 < 512
#define NSLOT     56                // 28 y-samples x {lo,hi}

__device__ __forceinline__ void axis_entry(float coord, float L,
                                           int& lo, int& hi, float& wlo, float& whi) {
    // torchvision ROIAlign bilinear edge handling
    const bool valid = (coord >= -1.0f) && (coord <= L);
    const float c   = fminf(fmaxf(coord, 0.0f), L - 1.0f);
    const float flo = floorf(c);
    const float fhi = fminf(flo + 1.0f, L - 1.0f);
    whi = c - flo;
    wlo = 1.0f - whi;
    if (!valid) { wlo = 0.0f; whi = 0.0f; }
    lo = (int)flo;
    hi = (int)fhi;
}

// pack two f32 -> two bf16 (round-to-nearest-even), lanes: lo=a, hi=b
__device__ __forceinline__ unsigned pack_bf16(float a, float b) {
    unsigned ua = __float_as_uint(a);
    unsigned ub = __float_as_uint(b);
    ua += 0x7FFFu + ((ua >> 16) & 1u);
    ub += 0x7FFFu + ((ub >> 16) & 1u);
    return (ua >> 16) | (ub & 0xFFFF0000u);
}
__device__ __forceinline__ float lo16(unsigned u) { return __uint_as_float(u << 16); }
__device__ __forceinline__ float hi16(unsigned u) { return __uint_as_float(u & 0xFFFF0000u); }

// NOTE: (256,3) not (256,4): the 4-bound clamps the allocator to 64 VGPR ->
// staging regs spill to scratch (+300 MB FETCH, 2.4x slower; rounds 9/10).
__global__ __launch_bounds__(256, 3) void roi_pool_kernel(
    const float* __restrict__ x0, const float* __restrict__ x1,
    const float* __restrict__ x2, const float* __restrict__ x3,
    const float* __restrict__ boxes, float* __restrict__ out)
{
    __shared__ uint4 tile[2][BUFL];   // bf16x8 cells (2 quads): 2 x 20 KB = 40 KB

    const int m    = blockIdx.x;   // box
    const int cblk = blockIdx.y;   // 32-channel chunk
    const int tid  = threadIdx.x;

    // ---- block-uniform box/level setup ----
    const float bxi = boxes[m*5+0];
    const float bx0 = boxes[m*5+1];
    const float by0 = boxes[m*5+2];
    const float bx1 = boxes[m*5+3];
    const float by1 = boxes[m*5+4];

    const float sz = sqrtf((bx1 - bx0) * (by1 - by0));
    int lvl = (int)floorf(4.0f + log2f(sz * (1.0f/224.0f) + 1e-8f));
    lvl = min(max(lvl, 2), 5) - 2;

    const float scales[4] = {0.25f, 0.125f, 0.0625f, 0.03125f};
    const int   dims[4]   = {256, 128, 64, 32};
    const float scale = scales[lvl];
    const int   W  = dims[lvl];
    const int   HW = W * W;
    const float Lf = (float)W;
    const float* feat = (lvl == 0) ? x0 : (lvl == 1) ? x1 : (lvl == 2) ? x2 : x3;
    const int bidx = (int)bxi;

    const float rx0 = bx0*scale - 0.5f;
    const float ry0 = by0*scale - 0.5f;
    const float binw = (bx1*scale - 0.5f - rx0) * (1.0f/14.0f);
    const float binh = (by1*scale - 0.5f - ry0) * (1.0f/14.0f);

    // y-row of slot k (k in [0,56)): sample s=k>>1, lo/hi by k&1  [validated round 3]
    auto slot_row = [&](int k) {
        const int s = k >> 1;
        const float coord = ry0 + ((float)(s >> 1) + 0.25f + 0.5f*(float)(s & 1)) * binh;
        int lo, hi; float a, b;
        axis_entry(coord, Lf, lo, hi, a, b);
        return (k & 1) ? hi : lo;
    };

    // ---- footprint extents (samples are monotone; first lo / last hi) ----
    int ymin, ymax, xmin, xmax;
    {
        int lo, hi; float a, b;
        axis_entry(ry0 +  0.25f*binh, Lf, lo, hi, a, b); ymin = lo;
        axis_entry(ry0 + 13.75f*binh, Lf, lo, hi, a, b); ymax = hi;
        axis_entry(rx0 +  0.25f*binw, Lf, lo, hi, a, b); xmin = lo;
        axis_entry(rx0 + 13.75f*binw, Lf, lo, hi, a, b); xmax = hi;
    }
    const int gx  = xmin & ~3;                     // 16B-aligned window start (W % 4 == 0)
    const int TW  = (xmax - gx + 1 + 3) & ~3;      // cols, multiple of 4 (float4 groups)
    const int TW4 = TW >> 2;                       // groups per row
    const int TWL = TW + 1;                        // LDS row stride: odd -> bank rotation
    const int NRn = ymax - ymin + 1;               // natural row count
    const bool slotY = (NRn > NSLOT);              // sparse rows: stage 56 sample slots
    int NRE = slotY ? NSLOT : NRn;                 // staged rows
    if (NRE * TWL > BUFL) NRE = BUFL / TWL;        // crash-guard (bound says unreachable)
    const int NG  = NRE * TW4;                     // global float4 groups per plane
    const int TCL = NRE * TWL;                     // LDS cells incl. row pad
    const int CMAX = TCL - 2;                      // last REAL cell; TCL-1 is the row pad

    // ---- per-thread staging groups (constant across quads) ----
    int  gbase[MAXG];   // global word offset of the 4-cell group (16B aligned)
    int  lbase[MAXG];   // LDS cell index of the group start
    bool gv[MAXG];
    #pragma unroll
    for (int s = 0; s < MAXG; ++s) {
        const int g = tid + (s << 8);
        gv[s] = (g < NG);
        const int gc = min(g, NG - 1);
        const int r  = gc / TW4;
        const int c4 = (gc - r * TW4) << 2;
        const int grow = slotY ? slot_row(r) : (ymin + r);
        gbase[s] = min(grow * W + gx + c4, HW - 4);  // safety; in-row by alignment proof
        lbase[s] = r * TWL + c4;
    }

    // ---- per-thread tap setup (bin = thread) ----
    const bool active = (tid < NBINS);
    const int  t  = active ? tid : (NBINS - 1);
    const int  ph = t / OUT_HW;
    const int  pw = t - ph * OUT_HW;

    int yl0, yh0, yl1, yh1, xl0, xh0, xl1, xh1;
    float wy0, wy1, wy2, wy3, wx0, wx1, wx2, wx3;
    axis_entry(ry0 + ((float)ph + 0.25f)*binh, Lf, yl0, yh0, wy0, wy1);
    axis_entry(ry0 + ((float)ph + 0.75f)*binh, Lf, yl1, yh1, wy2, wy3);
    axis_entry(rx0 + ((float)pw + 0.25f)*binw, Lf, xl0, xh0, wx0, wx1);
    axis_entry(rx0 + ((float)pw + 0.75f)*binw, Lf, xl1, xh1, wx2, wx3);
    wy0 *= 0.25f; wy1 *= 0.25f; wy2 *= 0.25f; wy3 *= 0.25f;  // fold 2x2 mean
    const float wyv[4] = { wy0, wy1, wy2, wy3 };

    // y tap rows: slot mode -> slots 4ph..4ph+3 (= samples 2ph,2ph+1 x lo/hi)
    int sr[4];
    if (slotY) { sr[0] = 4*ph; sr[1] = 4*ph + 1; sr[2] = 4*ph + 2; sr[3] = 4*ph + 3; }
    else       { sr[0] = yl0 - ymin; sr[1] = yh0 - ymin; sr[2] = yl1 - ymin; sr[3] = yh1 - ymin; }
    const int sc[4] = { xl0 - gx, xh0 - gx, xl1 - gx, xh1 - gx };

    int wq[16];   // tap cell indices; clamp targets a WRITTEN cell (never the row pad)
    #pragma unroll
    for (int i = 0; i < 4; ++i) {
        #pragma unroll
        for (int j = 0; j < 4; ++j) {
            wq[i*4 + j] = min(sr[i] * TWL + sc[j], CMAX);
        }
    }

    const float* fb = feat + ((size_t)bidx * C_TOTAL + (size_t)cblk * C_PER_BLK) * HW;
    float* ob = out + ((size_t)m * C_TOTAL + (size_t)cblk * C_PER_BLK) * NBINS + tid;

    // ---- staging: coalesced float4 loads -> pack bf16 -> b64 half-cell writes ----
    float4 stg[MAXG][4];   // [group][channel] -- single buffer (R17 lesson: two spill)

    auto LOADQ = [&](int qd) {   // quad qd = 4 channel planes
        const float* f0 = fb + (size_t)qd * 4 * HW;
        const float* f1 = f0 + HW;
        const float* f2 = f1 + HW;
        const float* f3 = f2 + HW;
        #pragma unroll
        for (int s = 0; s < MAXG; ++s) {
            stg[s][0] = *(const float4*)(f0 + gbase[s]);
            stg[s][1] = *(const float4*)(f1 + gbase[s]);
            stg[s][2] = *(const float4*)(f2 + gbase[s]);
            stg[s][3] = *(const float4*)(f3 + gbase[s]);
        }
    };
    // half=0: lo 8B of cell (quad A ch0-3), half=1: hi 8B (quad B ch4-7)
    auto WRITEH = [&](uint4* dst, int half) {
        uint2* d2 = (uint2*)dst;
        #pragma unroll
        for (int s = 0; s < MAXG; ++s)
            if (gv[s]) {
                const int b = (lbase[s] << 1) + half;
                d2[b + 0] = make_uint2(pack_bf16(stg[s][0].x, stg[s][1].x),
                                       pack_bf16(stg[s][2].x, stg[s][3].x));
                d2[b + 2] = make_uint2(pack_bf16(stg[s][0].y, stg[s][1].y),
                                       pack_bf16(stg[s][2].y, stg[s][3].y));
                d2[b + 4] = make_uint2(pack_bf16(stg[s][0].z, stg[s][1].z),
                                       pack_bf16(stg[s][2].z, stg[s][3].z));
                d2[b + 6] = make_uint2(pack_bf16(stg[s][0].w, stg[s][1].w),
                                       pack_bf16(stg[s][2].w, stg[s][3].w));
            }
    };

    // ---- prologue: stage octet 0 (quads 0,1) into buffer 0 ----
    LOADQ(0);
    WRITEH(&tile[0][0], 0);
    LOADQ(1);
    WRITEH(&tile[0][0], 1);

    // ---- octet loop: 4 barriers. Quad-A loads hoisted pre-barrier (covered
    //      by barrier + taps 0-1); quad-B loads covered by taps 2-3 + stores.
    for (int o = 0; o < NOCT; ++o) {
        const bool more = (o + 1 < NOCT);
        if (more) LOADQ(2*o + 2);               // quad A of next octet, in flight

        __syncthreads();   // stage(o) visible; all waves done reading buf (o+1)&1

        const uint4* bp = &tile[o & 1][0];
        uint4* bn = &tile[(o + 1) & 1][0];
        float v0 = 0, v1 = 0, v2 = 0, v3 = 0, v4 = 0, v5 = 0, v6 = 0, v7 = 0;

        #pragma unroll
        for (int i = 0; i < 2; ++i) {           // taps 0-1
            const uint4 c0 = bp[wq[4*i + 0]];
            const uint4 c1 = bp[wq[4*i + 1]];
            const uint4 c2 = bp[wq[4*i + 2]];
            const uint4 c3 = bp[wq[4*i + 3]];
            const float wyi = wyv[i];
            v0 += wyi * (wx0*lo16(c0.x) + wx1*lo16(c1.x) + wx2*lo16(c2.x) + wx3*lo16(c3.x));
            v1 += wyi * (wx0*hi16(c0.x) + wx1*hi16(c1.x) + wx2*hi16(c2.x) + wx3*hi16(c3.x));
            v2 += wyi * (wx0*lo16(c0.y) + wx1*lo16(c1.y) + wx2*lo16(c2.y) + wx3*lo16(c3.y));
            v3 += wyi * (wx0*hi16(c0.y) + wx1*hi16(c1.y) + wx2*hi16(c2.y) + wx3*hi16(c3.y));
            v4 += wyi * (wx0*lo16(c0.z) + wx1*lo16(c1.z) + wx2*lo16(c2.z) + wx3*lo16(c3.z));
            v5 += wyi * (wx0*hi16(c0.z) + wx1*hi16(c1.z) + wx2*hi16(c2.z) + wx3*hi16(c3.z));
            v6 += wyi * (wx0*lo16(c0.w) + wx1*lo16(c1.w) + wx2*lo16(c2.w) + wx3*lo16(c3.w));
            v7 += wyi * (wx0*hi16(c0.w) + wx1*hi16(c1.w) + wx2*hi16(c2.w) + wx3*hi16(c3.w));
        }

        if (more) {
            WRITEH(bn, 0);                      // quad A half (loads long in flight)
            LOADQ(2*o + 3);                     // quad B loads: covered by taps 2-3 + stores
        }

        #pragma unroll
        for (int i = 2; i < 4; ++i) {           // taps 2-3
            const uint4 c0 = bp[wq[4*i + 0]];
            const uint4 c1 = bp[wq[4*i + 1]];
            const uint4 c2 = bp[wq[4*i + 2]];
            const uint4 c3 = bp[wq[4*i + 3]];
            const float wyi = wyv[i];
            v0 += wyi * (wx0*lo16(c0.x) + wx1*lo16(c1.x) + wx2*lo16(c2.x) + wx3*lo16(c3.x));
            v1 += wyi * (wx0*hi16(c0.x) + wx1*hi16(c1.x) + wx2*hi16(c2.x) + wx3*hi16(c3.x));
            v2 += wyi * (wx0*lo16(c0.y) + wx1*lo16(c1.y) + wx2*lo16(c2.y) + wx3*lo16(c3.y));
            v3 += wyi * (wx0*hi16(c0.y) + wx1*hi16(c1.y) + wx2*hi16(c2.y) + wx3*hi16(c3.y));
            v4 += wyi * (wx0*lo16(c0.z) + wx1*lo16(c1.z) + wx2*lo16(c2.z) + wx3*lo16(c3.z));
            v5 += wyi * (wx0*hi16(c0.z) + wx1*hi16(c1.z) + wx2*hi16(c2.z) + wx3*hi16(c3.z));
            v6 += wyi * (wx0*lo16(c0.w) + wx1*lo16(c1.w) + wx2*lo16(c2.w) + wx3*lo16(c3.w));
            v7 += wyi * (wx0*hi16(c0.w) + wx1*hi16(c1.w) + wx2*hi16(c2.w) + wx3*hi16(c3.w));
        }

        if (active) {
            float* oc = ob + (size_t)(8*o) * NBINS;
            oc[0]                  = v0;
            oc[(size_t)1 * NBINS]  = v1;
            oc[(size_t)2 * NBINS]  = v2;
            oc[(size_t)3 * NBINS]  = v3;
            oc[(size_t)4 * NBINS]  = v4;
            oc[(size_t)5 * NBINS]  = v5;
            oc[(size_t)6 * NBINS]  = v6;
            oc[(size_t)7 * NBINS]  = v7;
        }

        if (more) WRITEH(bn, 1);                // quad B half; drained by next barrier
    }
}

extern "C" void kernel_launch(void* const* d_in, const int* in_sizes, int n_in,
                              void* d_out, int out_size, void* d_ws, size_t ws_size,
                              hipStream_t stream) {
    const float* x0    = (const float*)d_in[0];
    const float* x1    = (const float*)d_in[1];
    const float* x2    = (const float*)d_in[2];
    const float* x3    = (const float*)d_in[3];
    const float* boxes = (const float*)d_in[4];
    float* out = (float*)d_out;

    dim3 grid(NBOXES, C_TOTAL / C_PER_BLK);
    dim3 block(256);
    roi_pool_kernel<<<grid, block, 0, stream>>>(x0, x1, x2, x3, boxes, out);
}

// Round 22
// 72.469 us; speedup vs baseline: 1.1030x; 1.1030x over previous
//
#include <hip/hip_runtime.h>
#include <stdint.h>

#define OUT_HW    14
#define NBINS     196               // 14*14
#define C_TOTAL   256
#define C_PER_BLK 16
#define NQUADS    (C_PER_BLK / 4)   // 4 channel-quads per block
#define NBOXES    512
#define BUFL      1280              // 8B cells per buffer (worst ~1232: NR=56, TWL<=22)
#define MAXG      2                 // float4 groups per thread: worst NG ~336 < 512
#define NSLOT     56                // 28 y-samples x {lo,hi}

__device__ __forceinline__ void axis_entry(float coord, float L,
                                           int& lo, int& hi, float& wlo, float& whi) {
    // torchvision ROIAlign bilinear edge handling
    const bool valid = (coord >= -1.0f) && (coord <= L);
    const float c   = fminf(fmaxf(coord, 0.0f), L - 1.0f);
    const float flo = floorf(c);
    const float fhi = fminf(flo + 1.0f, L - 1.0f);
    whi = c - flo;
    wlo = 1.0f - whi;
    if (!valid) { wlo = 0.0f; whi = 0.0f; }
    lo = (int)flo;
    hi = (int)fhi;
}

// pack two f32 -> two bf16 (round-to-nearest-even), lanes: lo=a, hi=b
__device__ __forceinline__ unsigned pack_bf16(float a, float b) {
    unsigned ua = __float_as_uint(a);
    unsigned ub = __float_as_uint(b);
    ua += 0x7FFFu + ((ua >> 16) & 1u);
    ub += 0x7FFFu + ((ub >> 16) & 1u);
    return (ua >> 16) | (ub & 0xFFFF0000u);
}
__device__ __forceinline__ float lo16(unsigned u) { return __uint_as_float(u << 16); }
__device__ __forceinline__ float hi16(unsigned u) { return __uint_as_float(u & 0xFFFF0000u); }

// NOTE: (256,3) not (256,4): the 4-bound clamps the allocator to 64 VGPR ->
// staging regs spill to scratch (+300 MB FETCH, 2.4x slower; rounds 9/10).
__global__ __launch_bounds__(256, 3) void roi_pool_kernel(
    const float* __restrict__ x0, const float* __restrict__ x1,
    const float* __restrict__ x2, const float* __restrict__ x3,
    const float* __restrict__ boxes, float* __restrict__ out)
{
    __shared__ uint2 tile[2][BUFL];   // bf16x4 cells: 2 x 10 KB = 20 KB

    const int m    = blockIdx.x;   // box
    const int cblk = blockIdx.y;   // 16-channel chunk
    const int tid  = threadIdx.x;

    // ---- block-uniform box/level setup ----
    const float bxi = boxes[m*5+0];
    const float bx0 = boxes[m*5+1];
    const float by0 = boxes[m*5+2];
    const float bx1 = boxes[m*5+3];
    const float by1 = boxes[m*5+4];

    const float sz = sqrtf((bx1 - bx0) * (by1 - by0));
    int lvl = (int)floorf(4.0f + log2f(sz * (1.0f/224.0f) + 1e-8f));
    lvl = min(max(lvl, 2), 5) - 2;

    const float scales[4] = {0.25f, 0.125f, 0.0625f, 0.03125f};
    const int   dims[4]   = {256, 128, 64, 32};
    const float scale = scales[lvl];
    const int   W  = dims[lvl];
    const int   HW = W * W;
    const float Lf = (float)W;
    const float* feat = (lvl == 0) ? x0 : (lvl == 1) ? x1 : (lvl == 2) ? x2 : x3;
    const int bidx = (int)bxi;

    const float rx0 = bx0*scale - 0.5f;
    const float ry0 = by0*scale - 0.5f;
    const float binw = (bx1*scale - 0.5f - rx0) * (1.0f/14.0f);
    const float binh = (by1*scale - 0.5f - ry0) * (1.0f/14.0f);

    // y-row of slot k (k in [0,56)): sample s=k>>1, lo/hi by k&1  [validated round 3]
    auto slot_row = [&](int k) {
        const int s = k >> 1;
        const float coord = ry0 + ((float)(s >> 1) + 0.25f + 0.5f*(float)(s & 1)) * binh;
        int lo, hi; float a, b;
        axis_entry(coord, Lf, lo, hi, a, b);
        return (k & 1) ? hi : lo;
    };

    // ---- footprint extents (samples are monotone; first lo / last hi) ----
    int ymin, ymax, xmin, xmax;
    {
        int lo, hi; float a, b;
        axis_entry(ry0 +  0.25f*binh, Lf, lo, hi, a, b); ymin = lo;
        axis_entry(ry0 + 13.75f*binh, Lf, lo, hi, a, b); ymax = hi;
        axis_entry(rx0 +  0.25f*binw, Lf, lo, hi, a, b); xmin = lo;
        axis_entry(rx0 + 13.75f*binw, Lf, lo, hi, a, b); xmax = hi;
    }
    const int gx  = xmin & ~3;                     // 16B-aligned window start (W % 4 == 0)
    const int TW  = (xmax - gx + 1 + 3) & ~3;      // cols, multiple of 4 (float4 groups)
    const int TW4 = TW >> 2;                       // groups per row
    const int TWL = TW + 1;                        // LDS row stride: odd -> bank rotation
    const int NRn = ymax - ymin + 1;               // natural row count
    const bool slotY = (NRn > NSLOT);              // sparse rows: stage 56 sample slots
    int NRE = slotY ? NSLOT : NRn;                 // staged rows
    if (NRE * TWL > BUFL) NRE = BUFL / TWL;        // crash-guard (bound says unreachable)
    const int NG  = NRE * TW4;                     // global float4 groups per plane
    const int TCL = NRE * TWL;                     // LDS cells incl. row pad
    const int CMAX = TCL - 2;                      // last REAL cell; TCL-1 is the row pad

    // ---- per-thread staging groups (constant across quads) ----
    int  gbase[MAXG];   // global word offset of the 4-cell group (16B aligned)
    int  lbase[MAXG];   // LDS cell index of the group start
    bool gv[MAXG];
    #pragma unroll
    for (int s = 0; s < MAXG; ++s) {
        const int g = tid + (s << 8);
        gv[s] = (g < NG);
        const int gc = min(g, NG - 1);
        const int r  = gc / TW4;
        const int c4 = (gc - r * TW4) << 2;
        const int grow = slotY ? slot_row(r) : (ymin + r);
        gbase[s] = min(grow * W + gx + c4, HW - 4);  // safety; in-row by alignment proof
        lbase[s] = r * TWL + c4;
    }

    // ---- per-thread tap setup (bin = thread) ----
    const bool active = (tid < NBINS);
    const int  t  = active ? tid : (NBINS - 1);
    const int  ph = t / OUT_HW;
    const int  pw = t - ph * OUT_HW;

    int yl0, yh0, yl1, yh1, xl0, xh0, xl1, xh1;
    float wy0, wy1, wy2, wy3, wx0, wx1, wx2, wx3;
    axis_entry(ry0 + ((float)ph + 0.25f)*binh, Lf, yl0, yh0, wy0, wy1);
    axis_entry(ry0 + ((float)ph + 0.75f)*binh, Lf, yl1, yh1, wy2, wy3);
    axis_entry(rx0 + ((float)pw + 0.25f)*binw, Lf, xl0, xh0, wx0, wx1);
    axis_entry(rx0 + ((float)pw + 0.75f)*binw, Lf, xl1, xh1, wx2, wx3);
    wy0 *= 0.25f; wy1 *= 0.25f; wy2 *= 0.25f; wy3 *= 0.25f;  // fold 2x2 mean
    const float wyv[4] = { wy0, wy1, wy2, wy3 };

    // y tap rows: slot mode -> slots 4ph..4ph+3 (= samples 2ph,2ph+1 x lo/hi)
    int sr[4];
    if (slotY) { sr[0] = 4*ph; sr[1] = 4*ph + 1; sr[2] = 4*ph + 2; sr[3] = 4*ph + 3; }
    else       { sr[0] = yl0 - ymin; sr[1] = yh0 - ymin; sr[2] = yl1 - ymin; sr[3] = yh1 - ymin; }
    const int sc[4] = { xl0 - gx, xh0 - gx, xl1 - gx, xh1 - gx };

    int wq[16];   // tap cell indices; clamp targets a WRITTEN cell (never the row pad)
    #pragma unroll
    for (int i = 0; i < 4; ++i) {
        #pragma unroll
        for (int j = 0; j < 4; ++j) {
            wq[i*4 + j] = min(sr[i] * TWL + sc[j], CMAX);
        }
    }

    const float* fb = feat + ((size_t)bidx * C_TOTAL + (size_t)cblk * C_PER_BLK) * HW;
    float* ob = out + ((size_t)m * C_TOTAL + (size_t)cblk * C_PER_BLK) * NBINS + tid;

    // ---- staging: coalesced float4 loads -> pack bf16 -> b64 cell writes ----
    float4 stg[MAXG][4];   // [group][channel]

    auto LOADQ = [&](int qd) {
        const float* f0 = fb + (size_t)qd * 4 * HW;
        const float* f1 = f0 + HW;
        const float* f2 = f1 + HW;
        const float* f3 = f2 + HW;
        #pragma unroll
        for (int s = 0; s < MAXG; ++s) {
            stg[s][0] = *(const float4*)(f0 + gbase[s]);
            stg[s][1] = *(const float4*)(f1 + gbase[s]);
            stg[s][2] = *(const float4*)(f2 + gbase[s]);
            stg[s][3] = *(const float4*)(f3 + gbase[s]);
        }
    };
    auto WRITEQ = [&](uint2* dst) {
        #pragma unroll
        for (int s = 0; s < MAXG; ++s)
            if (gv[s]) {
                uint2* d = dst + lbase[s];
                d[0] = make_uint2(pack_bf16(stg[s][0].x, stg[s][1].x),
                                  pack_bf16(stg[s][2].x, stg[s][3].x));
                d[1] = make_uint2(pack_bf16(stg[s][0].y, stg[s][1].y),
                                  pack_bf16(stg[s][2].y, stg[s][3].y));
                d[2] = make_uint2(pack_bf16(stg[s][0].z, stg[s][1].z),
                                  pack_bf16(stg[s][2].z, stg[s][3].z));
                d[3] = make_uint2(pack_bf16(stg[s][0].w, stg[s][1].w),
                                  pack_bf16(stg[s][2].w, stg[s][3].w));
            }
    };

    // ---- prologue: stage quad 0 into buffer 0 ----
    LOADQ(0);
    WRITEQ(&tile[0][0]);

    // ---- quad loop: LOADQ(p+1) hoisted above the barrier (no LDS hazard;
    //      loads touch only global+regs). Round-19/20 proven schedule.
    for (int p = 0; p < NQUADS; ++p) {
        const bool more = (p + 1 < NQUADS);
        if (more) LOADQ(p + 1);                 // in flight across barrier + compute

        __syncthreads();   // stage(p) visible; all waves done reading buf (p+1)&1

        const uint2* bp = &tile[p & 1][0];
        float vx = 0.0f, vy = 0.0f, vz = 0.0f, vw = 0.0f;
        #pragma unroll
        for (int i = 0; i < 4; ++i) {
            const uint2 c0 = bp[wq[4*i + 0]];
            const uint2 c1 = bp[wq[4*i + 1]];
            const uint2 c2 = bp[wq[4*i + 2]];
            const uint2 c3 = bp[wq[4*i + 3]];
            const float wyi = wyv[i];
            vx += wyi * (wx0*lo16(c0.x) + wx1*lo16(c1.x) + wx2*lo16(c2.x) + wx3*lo16(c3.x));
            vy += wyi * (wx0*hi16(c0.x) + wx1*hi16(c1.x) + wx2*hi16(c2.x) + wx3*hi16(c3.x));
            vz += wyi * (wx0*lo16(c0.y) + wx1*lo16(c1.y) + wx2*lo16(c2.y) + wx3*lo16(c3.y));
            vw += wyi * (wx0*hi16(c0.y) + wx1*hi16(c1.y) + wx2*hi16(c2.y) + wx3*hi16(c3.y));
        }
        if (active) {
            ob[(size_t)(4*p + 0) * NBINS] = vx;
            ob[(size_t)(4*p + 1) * NBINS] = vy;
            ob[(size_t)(4*p + 2) * NBINS] = vz;
            ob[(size_t)(4*p + 3) * NBINS] = vw;
        }
        if (more) WRITEQ(&tile[(p + 1) & 1][0]);   // drained by the next barrier
    }
}

extern "C" void kernel_launch(void* const* d_in, const int* in_sizes, int n_in,
                              void* d_out, int out_size, void* d_ws, size_t ws_size,
                              hipStream_t stream) {
    const float* x0    = (const float*)d_in[0];
    const float* x1    = (const float*)d_in[1];
    const float* x2    = (const float*)d_in[2];
    const float* x3    = (const float*)d_in[3];
    const float* boxes = (const float*)d_in[4];
    float* out = (float*)d_out;

    dim3 grid(NBOXES, C_TOTAL / C_PER_BLK);
    dim3 block(256);
    roi_pool_kernel<<<grid, block, 0, stream>>>(x0, x1, x2, x3, boxes, out);
}

// Round 24
// 67.446 us; speedup vs baseline: 1.1851x; 1.0745x over previous
//
#include <hip/hip_runtime.h>
#include <stdint.h>

#define OUT_HW    14
#define NBINS     196               // 14*14
#define C_TOTAL   256
#define C_PER_BLK 16
#define NQUADS    (C_PER_BLK / 4)   // 4 channel-quads per block
#define NBOXES    512
#define BUFL      1280              // 8B cells per buffer (worst ~1232: NR=56, TWL<=22)
#define MAXG      2                 // float4 groups per thread: worst NG ~336 < 512
#define NSLOT     56                // 28 y-samples x {lo,hi}

typedef __fp16 half2_t __attribute__((ext_vector_type(2)));

__device__ __forceinline__ void axis_entry(float coord, float L,
                                           int& lo, int& hi, float& wlo, float& whi) {
    // torchvision ROIAlign bilinear edge handling
    const bool valid = (coord >= -1.0f) && (coord <= L);
    const float c   = fminf(fmaxf(coord, 0.0f), L - 1.0f);
    const float flo = floorf(c);
    const float fhi = fminf(flo + 1.0f, L - 1.0f);
    whi = c - flo;
    wlo = 1.0f - whi;
    if (!valid) { wlo = 0.0f; whi = 0.0f; }
    lo = (int)flo;
    hi = (int)fhi;
}

// pack two f32 -> two f16 (round-toward-zero), single v_cvt_pkrtz_f16_f32
__device__ __forceinline__ unsigned pack_f16(float a, float b) {
    half2_t h = __builtin_amdgcn_cvt_pkrtz(a, b);
    unsigned u; __builtin_memcpy(&u, &h, 4);
    return u;
}
// f16 halves -> f32 (compiler folds into v_fma_mix_f32 / v_cvt_f32_f16 op_sel)
__device__ __forceinline__ float plo(unsigned u) {
    half2_t h; __builtin_memcpy(&h, &u, 4); return (float)h.x;
}
__device__ __forceinline__ float phi(unsigned u) {
    half2_t h; __builtin_memcpy(&h, &u, 4); return (float)h.y;
}

// NOTE: (256,3) not (256,4): the 4-bound clamps the allocator to 64 VGPR ->
// staging regs spill to scratch (+300 MB FETCH, 2.4x slower; rounds 9/10).
__global__ __launch_bounds__(256, 3) void roi_pool_kernel(
    const float* __restrict__ x0, const float* __restrict__ x1,
    const float* __restrict__ x2, const float* __restrict__ x3,
    const float* __restrict__ boxes, float* __restrict__ out)
{
    __shared__ uint2 tile[2][BUFL];   // f16x4 cells: 2 x 10 KB = 20 KB

    const int m    = blockIdx.x;   // box
    const int cblk = blockIdx.y;   // 16-channel chunk
    const int tid  = threadIdx.x;

    // ---- block-uniform box/level setup ----
    const float bxi = boxes[m*5+0];
    const float bx0 = boxes[m*5+1];
    const float by0 = boxes[m*5+2];
    const float bx1 = boxes[m*5+3];
    const float by1 = boxes[m*5+4];

    const float sz = sqrtf((bx1 - bx0) * (by1 - by0));
    int lvl = (int)floorf(4.0f + log2f(sz * (1.0f/224.0f) + 1e-8f));
    lvl = min(max(lvl, 2), 5) - 2;

    const float scales[4] = {0.25f, 0.125f, 0.0625f, 0.03125f};
    const int   dims[4]   = {256, 128, 64, 32};
    const float scale = scales[lvl];
    const int   W  = dims[lvl];
    const int   HW = W * W;
    const float Lf = (float)W;
    const float* feat = (lvl == 0) ? x0 : (lvl == 1) ? x1 : (lvl == 2) ? x2 : x3;
    const int bidx = (int)bxi;

    const float rx0 = bx0*scale - 0.5f;
    const float ry0 = by0*scale - 0.5f;
    const float binw = (bx1*scale - 0.5f - rx0) * (1.0f/14.0f);
    const float binh = (by1*scale - 0.5f - ry0) * (1.0f/14.0f);

    // y-row of slot k (k in [0,56)): sample s=k>>1, lo/hi by k&1  [validated round 3]
    auto slot_row = [&](int k) {
        const int s = k >> 1;
        const float coord = ry0 + ((float)(s >> 1) + 0.25f + 0.5f*(float)(s & 1)) * binh;
        int lo, hi; float a, b;
        axis_entry(coord, Lf, lo, hi, a, b);
        return (k & 1) ? hi : lo;
    };

    // ---- footprint extents (samples are monotone; first lo / last hi) ----
    int ymin, ymax, xmin, xmax;
    {
        int lo, hi; float a, b;
        axis_entry(ry0 +  0.25f*binh, Lf, lo, hi, a, b); ymin = lo;
        axis_entry(ry0 + 13.75f*binh, Lf, lo, hi, a, b); ymax = hi;
        axis_entry(rx0 +  0.25f*binw, Lf, lo, hi, a, b); xmin = lo;
        axis_entry(rx0 + 13.75f*binw, Lf, lo, hi, a, b); xmax = hi;
    }
    const int gx  = xmin & ~3;                     // 16B-aligned window start (W % 4 == 0)
    const int TW  = (xmax - gx + 1 + 3) & ~3;      // cols, multiple of 4 (float4 groups)
    const int TW4 = TW >> 2;                       // groups per row
    const int TWL = TW + 1;                        // LDS row stride: odd -> bank rotation
    const int NRn = ymax - ymin + 1;               // natural row count
    const bool slotY = (NRn > NSLOT);              // sparse rows: stage 56 sample slots
    int NRE = slotY ? NSLOT : NRn;                 // staged rows
    if (NRE * TWL > BUFL) NRE = BUFL / TWL;        // crash-guard (bound says unreachable)
    const int NG  = NRE * TW4;                     // global float4 groups per plane
    const int TCL = NRE * TWL;                     // LDS cells incl. row pad
    const int CMAX = TCL - 2;                      // last REAL cell; TCL-1 is the row pad

    // ---- per-thread staging groups (constant across quads) ----
    int  gbase[MAXG];   // global word offset of the 4-cell group (16B aligned)
    int  lbase[MAXG];   // LDS cell index of the group start
    bool gv[MAXG];
    #pragma unroll
    for (int s = 0; s < MAXG; ++s) {
        const int g = tid + (s << 8);
        gv[s] = (g < NG);
        const int gc = min(g, NG - 1);
        const int r  = gc / TW4;
        const int c4 = (gc - r * TW4) << 2;
        const int grow = slotY ? slot_row(r) : (ymin + r);
        gbase[s] = min(grow * W + gx + c4, HW - 4);  // safety; in-row by alignment proof
        lbase[s] = r * TWL + c4;
    }

    // ---- per-thread tap setup (bin = thread) ----
    const bool active = (tid < NBINS);
    const int  t  = active ? tid : (NBINS - 1);
    const int  ph = t / OUT_HW;
    const int  pw = t - ph * OUT_HW;

    int yl0, yh0, yl1, yh1, xl0, xh0, xl1, xh1;
    float wy0, wy1, wy2, wy3, wx0, wx1, wx2, wx3;
    axis_entry(ry0 + ((float)ph + 0.25f)*binh, Lf, yl0, yh0, wy0, wy1);
    axis_entry(ry0 + ((float)ph + 0.75f)*binh, Lf, yl1, yh1, wy2, wy3);
    axis_entry(rx0 + ((float)pw + 0.25f)*binw, Lf, xl0, xh0, wx0, wx1);
    axis_entry(rx0 + ((float)pw + 0.75f)*binw, Lf, xl1, xh1, wx2, wx3);
    wy0 *= 0.25f; wy1 *= 0.25f; wy2 *= 0.25f; wy3 *= 0.25f;  // fold 2x2 mean
    const float wyv[4] = { wy0, wy1, wy2, wy3 };
    const float wxv[4] = { wx0, wx1, wx2, wx3 };

    // y tap rows: slot mode -> slots 4ph..4ph+3 (= samples 2ph,2ph+1 x lo/hi)
    int sr[4];
    if (slotY) { sr[0] = 4*ph; sr[1] = 4*ph + 1; sr[2] = 4*ph + 2; sr[3] = 4*ph + 3; }
    else       { sr[0] = yl0 - ymin; sr[1] = yh0 - ymin; sr[2] = yl1 - ymin; sr[3] = yh1 - ymin; }
    const int sc[4] = { xl0 - gx, xh0 - gx, xl1 - gx, xh1 - gx };

    int   wq[16];   // tap cell indices; clamp targets a WRITTEN cell (never the row pad)
    float wt[16];   // fused tap weights: (0.25*wyi) * wxj, precomputed once
    #pragma unroll
    for (int i = 0; i < 4; ++i) {
        #pragma unroll
        for (int j = 0; j < 4; ++j) {
            wq[i*4 + j] = min(sr[i] * TWL + sc[j], CMAX);
            wt[i*4 + j] = wyv[i] * wxv[j];
        }
    }

    const float* fb = feat + ((size_t)bidx * C_TOTAL + (size_t)cblk * C_PER_BLK) * HW;
    float* ob = out + ((size_t)m * C_TOTAL + (size_t)cblk * C_PER_BLK) * NBINS + tid;

    // ---- staging: coalesced float4 loads -> pack f16 -> b64 cell writes ----
    float4 stg[MAXG][4];   // [group][channel]

    auto LOADQ = [&](int qd) {
        const float* f0 = fb + (size_t)qd * 4 * HW;
        const float* f1 = f0 + HW;
        const float* f2 = f1 + HW;
        const float* f3 = f2 + HW;
        #pragma unroll
        for (int s = 0; s < MAXG; ++s) {
            stg[s][0] = *(const float4*)(f0 + gbase[s]);
            stg[s][1] = *(const float4*)(f1 + gbase[s]);
            stg[s][2] = *(const float4*)(f2 + gbase[s]);
            stg[s][3] = *(const float4*)(f3 + gbase[s]);
        }
    };
    auto WRITEQ = [&](uint2* dst) {
        #pragma unroll
        for (int s = 0; s < MAXG; ++s)
            if (gv[s]) {
                uint2* d = dst + lbase[s];
                d[0] = make_uint2(pack_f16(stg[s][0].x, stg[s][1].x),
                                  pack_f16(stg[s][2].x, stg[s][3].x));
                d[1] = make_uint2(pack_f16(stg[s][0].y, stg[s][1].y),
                                  pack_f16(stg[s][2].y, stg[s][3].y));
                d[2] = make_uint2(pack_f16(stg[s][0].z, stg[s][1].z),
                                  pack_f16(stg[s][2].z, stg[s][3].z));
                d[3] = make_uint2(pack_f16(stg[s][0].w, stg[s][1].w),
                                  pack_f16(stg[s][2].w, stg[s][3].w));
            }
    };

    // ---- prologue: stage quad 0 into buffer 0 ----
    LOADQ(0);
    WRITEQ(&tile[0][0]);

    // ---- quad loop: LOADQ(p+1) hoisted above the barrier (no LDS hazard;
    //      loads touch only global+regs). Round-19/20 proven schedule.
    for (int p = 0; p < NQUADS; ++p) {
        const bool more = (p + 1 < NQUADS);
        if (more) LOADQ(p + 1);                 // in flight across barrier + compute

        __syncthreads();   // stage(p) visible; all waves done reading buf (p+1)&1

        const uint2* bp = &tile[p & 1][0];
        float vx = 0.0f, vy = 0.0f, vz = 0.0f, vw = 0.0f;
        #pragma unroll
        for (int k = 0; k < 16; ++k) {
            const uint2  c = bp[wq[k]];
            const float  w = wt[k];
            vx = fmaf(w, plo(c.x), vx);         // v_fma_mix_f32 candidates
            vy = fmaf(w, phi(c.x), vy);
            vz = fmaf(w, plo(c.y), vz);
            vw = fmaf(w, phi(c.y), vw);
        }
        if (active) {
            ob[(size_t)(4*p + 0) * NBINS] = vx;
            ob[(size_t)(4*p + 1) * NBINS] = vy;
            ob[(size_t)(4*p + 2) * NBINS] = vz;
            ob[(size_t)(4*p + 3) * NBINS] = vw;
        }
        if (more) WRITEQ(&tile[(p + 1) & 1][0]);   // drained by the next barrier
    }
}

extern "C" void kernel_launch(void* const* d_in, const int* in_sizes, int n_in,
                              void* d_out, int out_size, void* d_ws, size_t ws_size,
                              hipStream_t stream) {
    const float* x0    = (const float*)d_in[0];
    const float* x1    = (const float*)d_in[1];
    const float* x2    = (const float*)d_in[2];
    const float* x3    = (const float*)d_in[3];
    const float* boxes = (const float*)d_in[4];
    float* out = (float*)d_out;

    dim3 grid(NBOXES, C_TOTAL / C_PER_BLK);
    dim3 block(256);
    roi_pool_kernel<<<grid, block, 0, stream>>>(x0, x1, x2, x3, boxes, out);
}